// Round 8
// baseline (211.715 us; speedup 1.0000x reference)
//
#include <hip/hip_runtime.h>
#include <cstddef>

#define BSZ   2
#define NN    384
#define DATOM 512
#define DPAIR 128
#define DHID  32

// ---------------------------------------------------------------------------
// Workspace layout (float offsets):
//   abuf [BSZ*NN][32]  fp32       offset 0         (24576 floats)
//   bbh  [BSZ*NN][32]  bf16 hi    offset 24576     (12288 floats)
//   bbl  [BSZ*NN][32]  bf16 lo    offset 36864     (12288 floats)
//   Th   [BSZ*NN][128][32] bf16   offset 49152     (1572864 floats)
//   Tl   [BSZ*NN][128][32] bf16   offset 1622016   (1572864 floats)
// ---------------------------------------------------------------------------

#define COMP4(v,i) ((i)==0?(v).x:(i)==1?(v).y:(i)==2?(v).z:(v).w)

typedef __attribute__((ext_vector_type(8))) short bf16x8;
typedef __attribute__((ext_vector_type(4))) float f32x4;

static __device__ __forceinline__ unsigned short f2bf(float x) {
    unsigned int u = __float_as_uint(x);
    u += 0x7fffu + ((u >> 16) & 1u);          // round-to-nearest-even
    return (unsigned short)(u >> 16);
}
static __device__ __forceinline__ float bf2f(unsigned short h) {
    return __uint_as_float(((unsigned int)h) << 16);
}

// Kernel A (round-2/6 verified, UNCHANGED): ab = (m @ W_in^T + b_in)*op_mask.
__global__ __launch_bounds__(256) void k_ab(
    const float* __restrict__ m, const float* __restrict__ op_mask,
    const float* __restrict__ W_in, const float* __restrict__ b_in,
    float* __restrict__ abuf,
    unsigned short* __restrict__ bbh, unsigned short* __restrict__ bbl)
{
    const int t   = threadIdx.x;
    const int h   = t >> 2;          // 0..63
    const int q   = t & 3;           // d-offset q*4, stride 16 floats
    const int row = blockIdx.x;      // b*NN + n

    const float* wrow = W_in + (size_t)h * DATOM + q * 4;
    const float* mrow = m + (size_t)row * DATOM + q * 4;
    float acc = 0.f;
#pragma unroll
    for (int k = 0; k < 32; ++k) {
        const float4 w  = *(const float4*)(wrow + k * 16);
        const float4 mm = *(const float4*)(mrow + k * 16);
        acc += w.x * mm.x + w.y * mm.y + w.z * mm.z + w.w * mm.w;
    }
    acc += __shfl_xor(acc, 1);
    acc += __shfl_xor(acc, 2);
    if (q == 0) {
        const float val = (acc + b_in[h]) * op_mask[row];
        if (h < DHID) {
            abuf[(size_t)row * DHID + h] = val;
        } else {
            const unsigned short hi = f2bf(val);
            const float lo = val - bf2f(hi);
            const size_t idx = (size_t)row * DHID + (h - DHID);
            bbh[idx] = hi;
            bbl[idx] = f2bf(lo);
        }
    }
}

// Kernel B (round-2/6 verified, UNCHANGED): T[i,p,y] = sum_x a[i,x]*W_out[...]
__global__ __launch_bounds__(256) void k_T(
    const float* __restrict__ abuf, const float* __restrict__ W_out,
    unsigned short* __restrict__ Th, unsigned short* __restrict__ Tl)
{
    __shared__ __align__(16) float alds[8 * DHID];
    const int t   = threadIdx.x;
    const int ig  = blockIdx.x >> 3;   // 0..95
    const int oct = blockIdx.x & 7;    // p base = oct*16
    const int r0  = ig * 8;            // flat (b*NN+i) base

    alds[t] = abuf[(size_t)r0 * DHID + t];
    __syncthreads();

    const int y  = t & 31;
    const int pg = t >> 5;             // 0..7

    float acc[2][8];
#pragma unroll
    for (int c = 0; c < 2; ++c)
#pragma unroll
        for (int i = 0; i < 8; ++i) acc[c][i] = 0.f;

#pragma unroll
    for (int xc = 0; xc < 8; ++xc) {
        float4 a4[8];
#pragma unroll
        for (int i = 0; i < 8; ++i)
            a4[i] = *(const float4*)&alds[i * DHID + xc * 4];  // broadcast
#pragma unroll
        for (int xi = 0; xi < 4; ++xi) {
            const int x = xc * 4 + xi;
            float w[2];
#pragma unroll
            for (int c = 0; c < 2; ++c) {
                const int p = oct * 16 + c * 8 + pg;
                w[c] = W_out[(size_t)p * (DHID * DHID) + x * DHID + y];
            }
#pragma unroll
            for (int i = 0; i < 8; ++i) {
                const float av = COMP4(a4[i], xi);
#pragma unroll
                for (int c = 0; c < 2; ++c) acc[c][i] += av * w[c];
            }
        }
    }
#pragma unroll
    for (int c = 0; c < 2; ++c) {
        const int p = oct * 16 + c * 8 + pg;
#pragma unroll
        for (int i = 0; i < 8; ++i) {
            const float v = acc[c][i];
            const unsigned short hi = f2bf(v);
            const float lo = v - bf2f(hi);
            const size_t idx = (((size_t)(r0 + i)) * DPAIR + p) * DHID + y;
            Th[idx] = hi;
            Tl[idx] = f2bf(lo);
        }
    }
}

// Kernel C (OCCUPANCY-TUNED swapped-operand MFMA): out[b,i,j,p] =
//   (sum_y bb[b,j,y]*T[b,i,p,y] + b_out[p]) * op_norm.
// Changes vs round 6 (all targeting latency/occupancy, same verified math):
//  - grid 1536: block = (b,i,j-half); 4 waves x 3 j-tiles each.
//  - p-tiles chunked 2x4: halves live fragment VGPRs so the allocator can
//    reach 4-5 waves/SIMD instead of 3.
//  - epilogue folded: bon = b_out*onorm precomputed; v = fma(acc,onorm,bon).
//  - nontemporal f32x4 (ext-vector) stores — __builtin_nontemporal_store
//    requires a clang vector type, not HIP's float4 struct.
__global__ __launch_bounds__(256) void k_main(
    const unsigned short* __restrict__ Th, const unsigned short* __restrict__ Tl,
    const unsigned short* __restrict__ bbh, const unsigned short* __restrict__ bbl,
    const float* __restrict__ b_out, const float* __restrict__ op_norm,
    float* __restrict__ out)
{
    const int t    = threadIdx.x;
    const int lane = t & 63;
    const int w    = t >> 6;           // wave 0..3
    const int lr   = lane & 15;        // col: j index within tile
    const int lg   = lane >> 4;        // k-group 0..3; D rows lg*4..lg*4+3
    const int y0   = lg * 8;           // k base (8 consecutive y per lane)

    const int bid  = blockIdx.x;       // 0..1535
    const int blk  = bid >> 1;         // b*NN + i
    const int half = bid & 1;          // j half (12 tiles each)
    const int b    = blk / NN;

    const unsigned short* tbh = Th + (size_t)blk * (DPAIR * DHID);
    const unsigned short* tbl = Tl + (size_t)blk * (DPAIR * DHID);
    const unsigned short* abh = bbh + (size_t)b * NN * DHID;
    const unsigned short* abl = bbl + (size_t)b * NN * DHID;

    const float onorm = op_norm[0];

#pragma unroll
    for (int ch = 0; ch < 2; ++ch) {
        // A-frags for p-tiles ch*4 .. ch*4+3: lane holds T[pt*16+lr][y0..+7].
        bf16x8 fh[4], fl[4];
#pragma unroll
        for (int pc = 0; pc < 4; ++pc) {
            const int pt = ch * 4 + pc;
            const size_t o = ((size_t)(pt * 16 + lr)) * DHID + y0;
            fh[pc] = *(const bf16x8*)(tbh + o);
            fl[pc] = *(const bf16x8*)(tbl + o);
        }
        // folded bias: bon = b_out[pt*16 + lg*4 .. +3] * onorm
        f32x4 bon[4];
#pragma unroll
        for (int pc = 0; pc < 4; ++pc) {
            const f32x4 bo = *((const f32x4*)b_out + (ch * 4 + pc) * 4 + lg);
            bon[pc] = bo * onorm;
        }

#pragma unroll
        for (int jj = 0; jj < 3; ++jj) {
            const int jt = half * 12 + w * 3 + jj;   // 0..23
            // B-frag: lane holds bb[jt*16+lr][y0..y0+7].
            const size_t ao = ((size_t)(jt * 16 + lr)) * DHID + y0;
            const bf16x8 bh = *(const bf16x8*)(abh + ao);
            const bf16x8 bl = *(const bf16x8*)(abl + ao);

            f32x4 acc[4];
#pragma unroll
            for (int pc = 0; pc < 4; ++pc) {
                f32x4 c = {0.f, 0.f, 0.f, 0.f};
                c = __builtin_amdgcn_mfma_f32_16x16x32_bf16(fh[pc], bh, c, 0, 0, 0);
                c = __builtin_amdgcn_mfma_f32_16x16x32_bf16(fh[pc], bl, c, 0, 0, 0);
                c = __builtin_amdgcn_mfma_f32_16x16x32_bf16(fl[pc], bh, c, 0, 0, 0);
                acc[pc] = c;
            }

            // D: row(p_local)=lg*4+r, col(j_local)=lr => f32x4 over p.
            float* orow = out + (((size_t)blk * NN) + jt * 16 + lr) * DPAIR
                              + ch * 64 + lg * 4;
#pragma unroll
            for (int pc = 0; pc < 4; ++pc) {
                f32x4 v;
                v[0] = fmaf(acc[pc][0], onorm, bon[pc][0]);
                v[1] = fmaf(acc[pc][1], onorm, bon[pc][1]);
                v[2] = fmaf(acc[pc][2], onorm, bon[pc][2]);
                v[3] = fmaf(acc[pc][3], onorm, bon[pc][3]);
                __builtin_nontemporal_store(v, (f32x4*)(orow + pc * 16));
            }
        }
    }
}

extern "C" void kernel_launch(void* const* d_in, const int* in_sizes, int n_in,
                              void* d_out, int out_size, void* d_ws, size_t ws_size,
                              hipStream_t stream)
{
    const float* m       = (const float*)d_in[0];
    const float* op_mask = (const float*)d_in[1];
    const float* op_norm = (const float*)d_in[2];
    const float* W_in    = (const float*)d_in[3];
    const float* b_in    = (const float*)d_in[4];
    const float* W_out   = (const float*)d_in[5];
    const float* b_out   = (const float*)d_in[6];
    float* out = (float*)d_out;

    float* ws = (float*)d_ws;
    float*          abuf = ws;                                   // 24576 f
    unsigned short* bbh  = (unsigned short*)(ws + 24576);        // 24576 sh
    unsigned short* bbl  = (unsigned short*)(ws + 36864);        // 24576 sh
    unsigned short* Th   = (unsigned short*)(ws + 49152);        // 3145728 sh
    unsigned short* Tl   = (unsigned short*)(ws + 49152 + 1572864);

    hipLaunchKernelGGL(k_ab,   dim3(BSZ * NN),           dim3(256), 0, stream,
                       m, op_mask, W_in, b_in, abuf, bbh, bbl);
    hipLaunchKernelGGL(k_T,    dim3((BSZ * NN / 8) * 8), dim3(256), 0, stream,
                       abuf, W_out, Th, Tl);
    hipLaunchKernelGGL(k_main, dim3(BSZ * NN * 2),       dim3(256), 0, stream,
                       Th, Tl, bbh, bbl, b_out, op_norm, out);
}

// Round 9
// 185.232 us; speedup vs baseline: 1.1430x; 1.1430x over previous
//
#include <hip/hip_runtime.h>
#include <cstddef>

#define BSZ   2
#define NN    384
#define DATOM 512
#define DPAIR 128
#define DHID  32

// ---------------------------------------------------------------------------
// REVERT to round-6 verified best (183.7 us). Round-7/8 occupancy experiment
// (grid x2, pt-chunking, nontemporal stores) regressed: compiler hoisted the
// chunked loads (no VGPR relief), T/bb re-reads doubled, nt-stores neutral.
// Model: k_ab+k_T ~10us, k_main ~26us (write-floor 24us), fill 93us (harness),
// tiny-dispatch overhead ~52us (harness) => ~183us composite floor.
//
// Workspace layout (float offsets):
//   abuf [BSZ*NN][32]  fp32       offset 0         (24576 floats)
//   bbh  [BSZ*NN][32]  bf16 hi    offset 24576     (12288 floats)
//   bbl  [BSZ*NN][32]  bf16 lo    offset 36864     (12288 floats)
//   Th   [BSZ*NN][128][32] bf16   offset 49152     (1572864 floats)
//   Tl   [BSZ*NN][128][32] bf16   offset 1622016   (1572864 floats)
// ---------------------------------------------------------------------------

#define COMP4(v,i) ((i)==0?(v).x:(i)==1?(v).y:(i)==2?(v).z:(v).w)

typedef __attribute__((ext_vector_type(8))) short bf16x8;
typedef __attribute__((ext_vector_type(4))) float f32x4;

static __device__ __forceinline__ unsigned short f2bf(float x) {
    unsigned int u = __float_as_uint(x);
    u += 0x7fffu + ((u >> 16) & 1u);          // round-to-nearest-even
    return (unsigned short)(u >> 16);
}
static __device__ __forceinline__ float bf2f(unsigned short h) {
    return __uint_as_float(((unsigned int)h) << 16);
}

// Kernel A: ab = (m @ W_in^T + b_in) * op_mask.
// block = ONE row; h = t>>2, q = t&3 split d 4-ways; quad-shfl reduce.
__global__ __launch_bounds__(256) void k_ab(
    const float* __restrict__ m, const float* __restrict__ op_mask,
    const float* __restrict__ W_in, const float* __restrict__ b_in,
    float* __restrict__ abuf,
    unsigned short* __restrict__ bbh, unsigned short* __restrict__ bbl)
{
    const int t   = threadIdx.x;
    const int h   = t >> 2;          // 0..63
    const int q   = t & 3;           // d-offset q*4, stride 16 floats
    const int row = blockIdx.x;      // b*NN + n

    const float* wrow = W_in + (size_t)h * DATOM + q * 4;
    const float* mrow = m + (size_t)row * DATOM + q * 4;
    float acc = 0.f;
#pragma unroll
    for (int k = 0; k < 32; ++k) {
        const float4 w  = *(const float4*)(wrow + k * 16);
        const float4 mm = *(const float4*)(mrow + k * 16);
        acc += w.x * mm.x + w.y * mm.y + w.z * mm.z + w.w * mm.w;
    }
    acc += __shfl_xor(acc, 1);
    acc += __shfl_xor(acc, 2);
    if (q == 0) {
        const float val = (acc + b_in[h]) * op_mask[row];
        if (h < DHID) {
            abuf[(size_t)row * DHID + h] = val;
        } else {
            const unsigned short hi = f2bf(val);
            const float lo = val - bf2f(hi);
            const size_t idx = (size_t)row * DHID + (h - DHID);
            bbh[idx] = hi;
            bbl[idx] = f2bf(lo);
        }
    }
}

// Kernel B: T[i,p,y] = sum_x a[i,x]*W_out[p,x*32+y]; split-bf16 epilogue.
__global__ __launch_bounds__(256) void k_T(
    const float* __restrict__ abuf, const float* __restrict__ W_out,
    unsigned short* __restrict__ Th, unsigned short* __restrict__ Tl)
{
    __shared__ __align__(16) float alds[8 * DHID];
    const int t   = threadIdx.x;
    const int ig  = blockIdx.x >> 3;   // 0..95
    const int oct = blockIdx.x & 7;    // p base = oct*16
    const int r0  = ig * 8;            // flat (b*NN+i) base

    alds[t] = abuf[(size_t)r0 * DHID + t];
    __syncthreads();

    const int y  = t & 31;
    const int pg = t >> 5;             // 0..7

    float acc[2][8];
#pragma unroll
    for (int c = 0; c < 2; ++c)
#pragma unroll
        for (int i = 0; i < 8; ++i) acc[c][i] = 0.f;

#pragma unroll
    for (int xc = 0; xc < 8; ++xc) {
        float4 a4[8];
#pragma unroll
        for (int i = 0; i < 8; ++i)
            a4[i] = *(const float4*)&alds[i * DHID + xc * 4];  // broadcast
#pragma unroll
        for (int xi = 0; xi < 4; ++xi) {
            const int x = xc * 4 + xi;
            float w[2];
#pragma unroll
            for (int c = 0; c < 2; ++c) {
                const int p = oct * 16 + c * 8 + pg;
                w[c] = W_out[(size_t)p * (DHID * DHID) + x * DHID + y];
            }
#pragma unroll
            for (int i = 0; i < 8; ++i) {
                const float av = COMP4(a4[i], xi);
#pragma unroll
                for (int c = 0; c < 2; ++c) acc[c][i] += av * w[c];
            }
        }
    }
#pragma unroll
    for (int c = 0; c < 2; ++c) {
        const int p = oct * 16 + c * 8 + pg;
#pragma unroll
        for (int i = 0; i < 8; ++i) {
            const float v = acc[c][i];
            const unsigned short hi = f2bf(v);
            const float lo = v - bf2f(hi);
            const size_t idx = (((size_t)(r0 + i)) * DPAIR + p) * DHID + y;
            Th[idx] = hi;
            Tl[idx] = f2bf(lo);
        }
    }
}

// Kernel C (round-6 verified, SWAPPED-OPERAND MFMA): out[b,i,j,p] =
//   (sum_y bb[b,j,y]*T[b,i,p,y] + b_out[p]) * op_norm.
// D[p][j] = T x bb; lane's 4 acc values are 4 CONSECUTIVE p => float4 stores.
// No LDS, no barriers; split-bf16 3-term MFMA (Ah*Bh + Ah*Bl + Al*Bh).
__global__ __launch_bounds__(256) void k_main(
    const unsigned short* __restrict__ Th, const unsigned short* __restrict__ Tl,
    const unsigned short* __restrict__ bbh, const unsigned short* __restrict__ bbl,
    const float* __restrict__ b_out, const float* __restrict__ op_norm,
    float* __restrict__ out)
{
    const int t    = threadIdx.x;
    const int lane = t & 63;
    const int w    = t >> 6;           // wave 0..3
    const int lr   = lane & 15;        // col: j index within tile
    const int lg   = lane >> 4;        // k-group 0..3; D rows lg*4..lg*4+3
    const int y0   = lg * 8;           // k base (8 consecutive y per lane)

    const int blk = blockIdx.x;        // b*NN + i
    const int b   = blk / NN;

    const unsigned short* tbh = Th + (size_t)blk * (DPAIR * DHID);
    const unsigned short* tbl = Tl + (size_t)blk * (DPAIR * DHID);
    const unsigned short* abh = bbh + (size_t)b * NN * DHID;
    const unsigned short* abl = bbl + (size_t)b * NN * DHID;

    // A-operand frags: A[m=p][k=y]; lane holds T[pt*16+lr][y0..y0+7].
    bf16x8 fh[8], fl[8];
#pragma unroll
    for (int pt = 0; pt < 8; ++pt) {
        const size_t o = ((size_t)(pt * 16 + lr)) * DHID + y0;
        fh[pt] = *(const bf16x8*)(tbh + o);
        fl[pt] = *(const bf16x8*)(tbl + o);
    }

    // bias: lane needs b_out[pt*16 + lg*4 .. +3] per p-tile.
    float4 bo4[8];
#pragma unroll
    for (int pt = 0; pt < 8; ++pt)
        bo4[pt] = ((const float4*)b_out)[pt * 4 + lg];
    const float onorm = op_norm[0];

#pragma unroll 2
    for (int jj = 0; jj < 6; ++jj) {
        const int jt = w * 6 + jj;
        // B-operand frag: B[k=y][n=j]; lane holds bb[jt*16+lr][y0..y0+7].
        const size_t ao = ((size_t)(jt * 16 + lr)) * DHID + y0;
        const bf16x8 bh = *(const bf16x8*)(abh + ao);
        const bf16x8 bl = *(const bf16x8*)(abl + ao);

        f32x4 acc[8];
#pragma unroll
        for (int pt = 0; pt < 8; ++pt) {
            f32x4 c = {0.f, 0.f, 0.f, 0.f};
            c = __builtin_amdgcn_mfma_f32_16x16x32_bf16(fh[pt], bh, c, 0, 0, 0);
            c = __builtin_amdgcn_mfma_f32_16x16x32_bf16(fh[pt], bl, c, 0, 0, 0);
            c = __builtin_amdgcn_mfma_f32_16x16x32_bf16(fl[pt], bh, c, 0, 0, 0);
            acc[pt] = c;
        }

        // D: row(p_local)=lg*4+r, col(j_local)=lr => float4 over p.
        float* orow = out + (((size_t)blk * NN) + jt * 16 + lr) * DPAIR + lg * 4;
#pragma unroll
        for (int pt = 0; pt < 8; ++pt) {
            float4 v;
            v.x = (acc[pt][0] + bo4[pt].x) * onorm;
            v.y = (acc[pt][1] + bo4[pt].y) * onorm;
            v.z = (acc[pt][2] + bo4[pt].z) * onorm;
            v.w = (acc[pt][3] + bo4[pt].w) * onorm;
            *(float4*)(orow + pt * 16) = v;
        }
    }
}

extern "C" void kernel_launch(void* const* d_in, const int* in_sizes, int n_in,
                              void* d_out, int out_size, void* d_ws, size_t ws_size,
                              hipStream_t stream)
{
    const float* m       = (const float*)d_in[0];
    const float* op_mask = (const float*)d_in[1];
    const float* op_norm = (const float*)d_in[2];
    const float* W_in    = (const float*)d_in[3];
    const float* b_in    = (const float*)d_in[4];
    const float* W_out   = (const float*)d_in[5];
    const float* b_out   = (const float*)d_in[6];
    float* out = (float*)d_out;

    float* ws = (float*)d_ws;
    float*          abuf = ws;                                   // 24576 f
    unsigned short* bbh  = (unsigned short*)(ws + 24576);        // 24576 sh
    unsigned short* bbl  = (unsigned short*)(ws + 36864);        // 24576 sh
    unsigned short* Th   = (unsigned short*)(ws + 49152);        // 3145728 sh
    unsigned short* Tl   = (unsigned short*)(ws + 49152 + 1572864);

    hipLaunchKernelGGL(k_ab,   dim3(BSZ * NN),           dim3(256), 0, stream,
                       m, op_mask, W_in, b_in, abuf, bbh, bbl);
    hipLaunchKernelGGL(k_T,    dim3((BSZ * NN / 8) * 8), dim3(256), 0, stream,
                       abuf, W_out, Th, Tl);
    hipLaunchKernelGGL(k_main, dim3(BSZ * NN),           dim3(256), 0, stream,
                       Th, Tl, bbh, bbl, b_out, op_norm, out);
}